// Round 5
// baseline (301.831 us; speedup 1.0000x reference)
//
#include <hip/hip_runtime.h>
#include <stdint.h>

#define NC 12
#define NHW (256*256)

typedef __attribute__((ext_vector_type(8))) short bf16x8;
typedef __attribute__((ext_vector_type(4))) float f32x4;
typedef __attribute__((ext_vector_type(4))) uint32_t u32x4;

// pack two f32 -> u32 of 2 bf16 (RNE); compiler fuses pairs to v_cvt_pk_bf16_f32
__device__ __forceinline__ uint32_t pkbf(float lo, float hi) {
    const uint16_t lu = __builtin_bit_cast(uint16_t, (__bf16)lo);
    const uint16_t hu = __builtin_bit_cast(uint16_t, (__bf16)hi);
    return (uint32_t)lu | ((uint32_t)hu << 16);
}

// Register-resident fused NCA step with a vertical sliding-window stencil.
// K-bijections (same on A and B, so contraction exact):
//   GEMM1 (w1[96x48]·yT): slot(s,g,j): s=0 -> col 12g+j ; s=1,j<4 -> col 12g+8+j ; else 0
//   GEMM2 (w2[12x96]·hT): slot(s2,g,j) -> col 32s2 + 16*(j>=4) + 4g + (j&3)
// GEMM1's D regs ARE GEMM2's B-frags (no LDS / no cross-lane exchange).
// Each wave walks 4 column-spans (16 px) down 8 rows, keeping 3 tap-rows
// (9 floats: 3 ch x 3 taps) in registers and prefetching row h+2 under the
// compute of row h -> 9 loads/step instead of 27, latency hidden.
__global__ __launch_bounds__(256, 3) void nca_fused4(
    const float* __restrict__ x, const float* __restrict__ w1,
    const float* __restrict__ b1, const float* __restrict__ w2,
    const float* __restrict__ rmask, float* __restrict__ out)
{
    const int tid  = threadIdx.x;
    const int lane = tid & 63;
    const int wv   = tid >> 6;
    const int g    = lane >> 4;   // 16-lane group
    const int p    = lane & 15;   // pixel col (B/D), weight row (A)
    const int c0   = 3 * g;      // this lane's first perception channel

    // ---- resident A fragments + bias ----
    bf16x8 a1[6][2];
    f32x4  biasv[6];
    #pragma unroll
    for (int t = 0; t < 6; ++t) {
        const int row = 16*t + p;
        const float4 fa = *reinterpret_cast<const float4*>(w1 + row*48 + 12*g + 0);
        const float4 fb = *reinterpret_cast<const float4*>(w1 + row*48 + 12*g + 4);
        const float4 fc = *reinterpret_cast<const float4*>(w1 + row*48 + 12*g + 8);
        u32x4 ua = { pkbf(fa.x, fa.y), pkbf(fa.z, fa.w), pkbf(fb.x, fb.y), pkbf(fb.z, fb.w) };
        u32x4 ub = { pkbf(fc.x, fc.y), pkbf(fc.z, fc.w), 0u, 0u };
        a1[t][0] = __builtin_bit_cast(bf16x8, ua);
        a1[t][1] = __builtin_bit_cast(bf16x8, ub);
        biasv[t] = *reinterpret_cast<const f32x4*>(b1 + 16*t + 4*g);
    }
    bf16x8 a2[3];
    #pragma unroll
    for (int s = 0; s < 3; ++s) {
        u32x4 u = {0u, 0u, 0u, 0u};
        if (p < NC) {
            const float4 wa = *reinterpret_cast<const float4*>(w2 + p*96 + 32*s + 4*g);
            const float4 wb = *reinterpret_cast<const float4*>(w2 + p*96 + 32*s + 16 + 4*g);
            u = (u32x4){ pkbf(wa.x, wa.y), pkbf(wa.z, wa.w), pkbf(wb.x, wb.y), pkbf(wb.z, wb.w) };
        }
        a2[s] = __builtin_bit_cast(bf16x8, u);
    }

    const int b  = blockIdx.x >> 5;
    const int h0 = (blockIdx.x & 31) * 8;   // 8-row strip
    const float* __restrict__ xb = x + (size_t)b * NC * NHW;
    const float* __restrict__ mb = rmask + (size_t)b * NHW;
    float* __restrict__ ob = out + (size_t)b * NC * NHW;

    #pragma unroll 1
    for (int gi = 0; gi < 4; ++gi) {
        const int grp = 4*wv + gi;          // wave owns 4 contiguous 16-px spans
        const int wc  = (grp << 4) + p;
        const int wm  = (wc - 1) & 255;
        const int wp  = (wc + 1) & 255;
        int off[9];                          // per-lane invariant tap offsets
        #pragma unroll
        for (int ci = 0; ci < 3; ++ci) {
            const int cb = (c0 + ci) * NHW;
            off[3*ci+0] = cb + wm; off[3*ci+1] = cb + wc; off[3*ci+2] = cb + wp;
        }

        float A[9], B[9], C[9];              // tap rows h-1, h, h+1
        {
            const float* rA = xb + (((h0 - 1) & 255) << 8);
            const float* rB = xb + (h0 << 8);
            const float* rC = xb + ((h0 + 1) << 8);   // h0+1 <= 249: no wrap
            #pragma unroll
            for (int q = 0; q < 9; ++q) A[q] = rA[off[q]];
            #pragma unroll
            for (int q = 0; q < 9; ++q) B[q] = rB[off[q]];
            #pragma unroll
            for (int q = 0; q < 9; ++q) C[q] = rC[off[q]];
        }

        #pragma unroll
        for (int i = 0; i < 8; ++i) {
            const int h    = h0 + i;
            const int hrow = h << 8;

            // prefetch tap-row h+2 under this step's compute
            float D[9];
            if (i < 7) {
                const float* rD = xb + (((h + 2) & 255) << 8);
                #pragma unroll
                for (int q = 0; q < 9; ++q) D[q] = rD[off[q]];
            }

            // ---- stencil from resident rows (no load wait) ----
            uint32_t yw[6];
            #pragma unroll
            for (int ci = 0; ci < 3; ++ci) {
                const float v0 = A[3*ci+0], v1 = A[3*ci+1], v2 = A[3*ci+2];
                const float v3 = B[3*ci+0], v4 = B[3*ci+1], v5 = B[3*ci+2];
                const float v6 = C[3*ci+0], v7 = C[3*ci+1], v8 = C[3*ci+2];
                const float fsx = (v2 - v0) + 2.f*(v5 - v3) + (v8 - v6);
                const float fsy = (v6 - v0) + 2.f*(v7 - v1) + (v8 - v2);
                const float flp = ((v0 + v2) + (v6 + v8)) + 2.f*((v1 + v3) + (v5 + v7)) - 12.f*v4;
                yw[2*ci]   = pkbf(v4, fsx);   // ident, sobel_x
                yw[2*ci+1] = pkbf(fsy, flp);  // sobel_xT, lap
            }
            const bf16x8 yf0 = __builtin_bit_cast(bf16x8, (u32x4){yw[0], yw[1], yw[2], yw[3]});
            const bf16x8 yf1 = __builtin_bit_cast(bf16x8, (u32x4){yw[4], yw[5], 0u, 0u});

            // ---- GEMM1: bias via C-in, ReLU, pack ----
            uint32_t pu[6][2];
            #pragma unroll
            for (int t = 0; t < 6; ++t) {
                f32x4 acc = biasv[t];
                acc = __builtin_amdgcn_mfma_f32_16x16x32_bf16(a1[t][0], yf0, acc, 0, 0, 0);
                acc = __builtin_amdgcn_mfma_f32_16x16x32_bf16(a1[t][1], yf1, acc, 0, 0, 0);
                pu[t][0] = pkbf(fmaxf(acc[0], 0.f), fmaxf(acc[1], 0.f));
                pu[t][1] = pkbf(fmaxf(acc[2], 0.f), fmaxf(acc[3], 0.f));
            }

            // ---- GEMM2: pu words ARE the B-frags under the K-bijection ----
            f32x4 acc2 = {0.f, 0.f, 0.f, 0.f};
            #pragma unroll
            for (int s2 = 0; s2 < 3; ++s2) {
                const u32x4 fb2 = { pu[2*s2][0], pu[2*s2][1], pu[2*s2+1][0], pu[2*s2+1][1] };
                acc2 = __builtin_amdgcn_mfma_f32_16x16x32_bf16(a2[s2], __builtin_bit_cast(bf16x8, fb2), acc2, 0, 0, 0);
            }

            // ---- epilogue ----
            const float um = floorf(mb[hrow + wc] + 0.5f);
            if (g < 3) {
                #pragma unroll
                for (int r = 0; r < 4; ++r) {
                    const int idx = (4*g + r) * NHW + hrow + wc;
                    ob[idx] = xb[idx] + acc2[r] * um;
                }
            }

            // ---- rotate window (renamed away by the unroll) ----
            #pragma unroll
            for (int q = 0; q < 9; ++q) { A[q] = B[q]; B[q] = C[q]; C[q] = D[q]; }
        }
    }
}

extern "C" void kernel_launch(void* const* d_in, const int* in_sizes, int n_in,
                              void* d_out, int out_size, void* d_ws, size_t ws_size,
                              hipStream_t stream) {
    const float* x  = (const float*)d_in[0];
    const float* w1 = (const float*)d_in[1];
    const float* b1 = (const float*)d_in[2];
    const float* w2 = (const float*)d_in[3];
    const float* rm = (const float*)d_in[4];
    float* out = (float*)d_out;
    nca_fused4<<<dim3(32 * 32), dim3(256), 0, stream>>>(x, w1, b1, w2, rm, out);
}

// Round 6
// 119.671 us; speedup vs baseline: 2.5222x; 2.5222x over previous
//
#include <hip/hip_runtime.h>
#include <stdint.h>

#define NC 12
#define NHW (256*256)

typedef __attribute__((ext_vector_type(8))) short bf16x8;
typedef __attribute__((ext_vector_type(4))) float f32x4;
typedef __attribute__((ext_vector_type(4))) uint32_t u32x4;

// pack two f32 -> u32 of 2 bf16 (RNE); compiler fuses pairs to v_cvt_pk_bf16_f32
__device__ __forceinline__ uint32_t pkbf(float lo, float hi) {
    const uint16_t lu = __builtin_bit_cast(uint16_t, (__bf16)lo);
    const uint16_t hu = __builtin_bit_cast(uint16_t, (__bf16)hi);
    return (uint32_t)lu | ((uint32_t)hu << 16);
}

// Opaque-asm pin: makes the value un-rematerializable so the compiler keeps it
// register-resident instead of re-loading/re-converting weights every iteration
// (r4/r5 disasm-level finding: VGPR=88 < the 84 regs of fragments alone).
#define PIN(v) asm volatile("" : "+v"(v))

// Fused NCA step, horizontal sweep (cache-line-friendly; r5's vertical walk
// cost 4.8x FETCH). K-bijections (same on A and B => contraction exact):
//   GEMM1 (w1[96x48]·yT): slot(s,g,j): s=0 -> col 12g+j ; s=1,j<4 -> col 12g+8+j
//   GEMM2 (w2[12x96]·hT): slot(s2,g,j) -> col 32s2 + 16*(j>=4) + 4g + (j&3)
// GEMM1's D regs ARE GEMM2's B-frags: no LDS, no cross-lane exchange.
__global__ __launch_bounds__(256, 3) void nca_fused5(
    const float* __restrict__ x, const float* __restrict__ w1,
    const float* __restrict__ b1, const float* __restrict__ w2,
    const float* __restrict__ rmask, float* __restrict__ out)
{
    const int tid  = threadIdx.x;
    const int lane = tid & 63;
    const int wv   = tid >> 6;
    const int g    = lane >> 4;   // 16-lane group
    const int p    = lane & 15;   // pixel col (B/D), weight row (A)
    const int c0   = 3 * g;       // this lane's first perception channel

    // ---- one-time weight fragment construction, then PIN resident ----
    u32x4 a1u[6][2];
    f32x4 biasv[6];
    #pragma unroll
    for (int t = 0; t < 6; ++t) {
        const int row = 16*t + p;
        const float4 fa = *reinterpret_cast<const float4*>(w1 + row*48 + 12*g + 0); // ch 3g   f0..3
        const float4 fb = *reinterpret_cast<const float4*>(w1 + row*48 + 12*g + 4); // ch 3g+1 f0..3
        const float4 fc = *reinterpret_cast<const float4*>(w1 + row*48 + 12*g + 8); // ch 3g+2 f0..3
        a1u[t][0] = (u32x4){ pkbf(fa.x, fa.y), pkbf(fa.z, fa.w), pkbf(fb.x, fb.y), pkbf(fb.z, fb.w) };
        a1u[t][1] = (u32x4){ pkbf(fc.x, fc.y), pkbf(fc.z, fc.w), 0u, 0u };
        biasv[t] = *reinterpret_cast<const f32x4*>(b1 + 16*t + 4*g);
        PIN(a1u[t][0]); PIN(a1u[t][1]); PIN(biasv[t]);
    }
    u32x4 a2u[3];
    #pragma unroll
    for (int s = 0; s < 3; ++s) {
        u32x4 u = {0u, 0u, 0u, 0u};
        if (p < NC) {
            const float4 wa = *reinterpret_cast<const float4*>(w2 + p*96 + 32*s + 4*g);      // k: 32s+4g+0..3
            const float4 wb = *reinterpret_cast<const float4*>(w2 + p*96 + 32*s + 16 + 4*g); // k: 32s+16+4g+0..3
            u = (u32x4){ pkbf(wa.x, wa.y), pkbf(wa.z, wa.w), pkbf(wb.x, wb.y), pkbf(wb.z, wb.w) };
        }
        a2u[s] = u;
        PIN(a2u[s]);
    }

    // grid: 2048 blocks = 32 batches x 64 four-row strips; wave owns one row
    const int b  = blockIdx.x >> 6;
    const int h  = (blockIdx.x & 63) * 4 + wv;
    const float* __restrict__ xb = x + (size_t)b * NC * NHW;
    const float* __restrict__ mb = rmask + (size_t)b * NHW;
    float* __restrict__ ob = out + (size_t)b * NC * NHW;

    const int hm = (h - 1) & 255;
    const int hp = (h + 1) & 255;
    const int hrow = h << 8;
    int rb[3][3];   // element offsets: this lane's 3 channels x 3 stencil rows
    #pragma unroll
    for (int ci = 0; ci < 3; ++ci) {
        const int cb = (c0 + ci) * NHW;
        rb[ci][0] = cb + (hm << 8);
        rb[ci][1] = cb + hrow;
        rb[ci][2] = cb + (hp << 8);
    }

    auto body = [&](const int wc, const int dm, const int dp) {
        // ---- perception: 3 channels/lane, 27 loads (imm offsets mostly) ----
        uint32_t yw[6];
        #pragma unroll
        for (int ci = 0; ci < 3; ++ci) {
            const float* r0 = xb + rb[ci][0] + wc;
            const float* r1 = xb + rb[ci][1] + wc;
            const float* r2 = xb + rb[ci][2] + wc;
            const float v0 = r0[dm], v1 = r0[0], v2 = r0[dp];
            const float v3 = r1[dm], v4 = r1[0], v5 = r1[dp];
            const float v6 = r2[dm], v7 = r2[0], v8 = r2[dp];
            const float fsx = (v2 - v0) + 2.f*(v5 - v3) + (v8 - v6);
            const float fsy = (v6 - v0) + 2.f*(v7 - v1) + (v8 - v2);
            const float flp = ((v0 + v2) + (v6 + v8)) + 2.f*((v1 + v3) + (v5 + v7)) - 12.f*v4;
            yw[2*ci]   = pkbf(v4, fsx);   // ident, sobel_x
            yw[2*ci+1] = pkbf(fsy, flp);  // sobel_xT, lap
        }
        const bf16x8 yf0 = __builtin_bit_cast(bf16x8, (u32x4){yw[0], yw[1], yw[2], yw[3]});
        const bf16x8 yf1 = __builtin_bit_cast(bf16x8, (u32x4){yw[4], yw[5], 0u, 0u});

        // ---- GEMM1: bias via C-in, ReLU, pack (lane (g,p): ch 16t+4g+0..3, px p) ----
        uint32_t pu[6][2];
        #pragma unroll
        for (int t = 0; t < 6; ++t) {
            f32x4 acc = biasv[t];
            acc = __builtin_amdgcn_mfma_f32_16x16x32_bf16(__builtin_bit_cast(bf16x8, a1u[t][0]), yf0, acc, 0, 0, 0);
            acc = __builtin_amdgcn_mfma_f32_16x16x32_bf16(__builtin_bit_cast(bf16x8, a1u[t][1]), yf1, acc, 0, 0, 0);
            pu[t][0] = pkbf(fmaxf(acc[0], 0.f), fmaxf(acc[1], 0.f));
            pu[t][1] = pkbf(fmaxf(acc[2], 0.f), fmaxf(acc[3], 0.f));
        }

        // ---- GEMM2: pu words ARE the B-frags under the K-bijection ----
        f32x4 acc2 = {0.f, 0.f, 0.f, 0.f};
        #pragma unroll
        for (int s2 = 0; s2 < 3; ++s2) {
            const u32x4 fb2 = { pu[2*s2][0], pu[2*s2][1], pu[2*s2+1][0], pu[2*s2+1][1] };
            acc2 = __builtin_amdgcn_mfma_f32_16x16x32_bf16(__builtin_bit_cast(bf16x8, a2u[s2]), __builtin_bit_cast(bf16x8, fb2), acc2, 0, 0, 0);
        }

        // ---- epilogue: out = x + upd * floor(rand + 0.5)  (x re-reads L1-hit) ----
        const float um = floorf(mb[hrow + wc] + 0.5f);
        if (g < 3) {
            #pragma unroll
            for (int r = 0; r < 4; ++r) {
                const int idx = (4*g + r) * NHW + hrow + wc;
                ob[idx] = xb[idx] + acc2[r] * um;
            }
        }
    };

    body(p, (p == 0) ? 255 : -1, 1);          // grp 0: left wrap on lane p==0
    #pragma unroll 1
    for (int grp = 1; grp < 15; ++grp)
        body((grp << 4) + p, -1, 1);          // middle: immediate offsets only
    body(240 + p, -1, (p == 15) ? -255 : 1);  // grp 15: right wrap on lane p==15
}

extern "C" void kernel_launch(void* const* d_in, const int* in_sizes, int n_in,
                              void* d_out, int out_size, void* d_ws, size_t ws_size,
                              hipStream_t stream) {
    const float* x  = (const float*)d_in[0];
    const float* w1 = (const float*)d_in[1];
    const float* b1 = (const float*)d_in[2];
    const float* w2 = (const float*)d_in[3];
    const float* rm = (const float*)d_in[4];
    float* out = (float*)d_out;
    nca_fused5<<<dim3(32 * 64), dim3(256), 0, stream>>>(x, w1, b1, w2, rm, out);
}